// Round 1
// baseline (172.095 us; speedup 1.0000x reference)
//
#include <hip/hip_runtime.h>
#include <math.h>

// SoftCodebook fused kernel v3 for MI355X (gfx950).
// p = softmax( (h/||h||) @ (proto/||proto||)^T / 0.1 ),  z = p @ proto
// v3: no LDS staging, no __syncthreads. Codebook is pre-swizzled by k_frag into
// per-lane MFMA B-fragment order in ws (128 KB, L2-resident); k_main loads B
// fragments directly global->VGPR (coalesced 16 B/lane). 1/||h|| is folded into
// the softmax slope post-GEMM so h converts to f16 raw at load (no hv[64] f32).
// LDS = 17 KB (wave-private p-transpose buffer only) -> occupancy VGPR-bound.

#define EPS 1e-12f
#define TAU_INV 10.0f

typedef _Float16 f16x8 __attribute__((ext_vector_type(8)));
typedef float f32x4 __attribute__((ext_vector_type(4)));

#define PB_STRIDE 136   // halves per pbuf row: 272 B (16B-aligned rows, <=2-way bank)

// ---------------------------------------------------------------------------
// k_prep: per-prototype L2 norm -> scale[128].  grid 128 x 64.
__global__ void k_prep(const float* __restrict__ proto, float* __restrict__ scale) {
    const int kp = blockIdx.x;
    const int lane = threadIdx.x;
    const float4 v = ((const float4*)(proto + kp * 256))[lane];
    float s = v.x * v.x + v.y * v.y + v.z * v.z + v.w * v.w;
    #pragma unroll
    for (int msk = 1; msk < 64; msk <<= 1) s += __shfl_xor(s, msk, 64);
    if (lane == 0) scale[kp] = fmaxf(sqrtf(s), EPS);
}

// ---------------------------------------------------------------------------
// k_frag: build per-lane B-fragment images (f16 cbar) in ws.  grid 128 x 64.
//   simB[(t*8+c)*64 + lane][j] = cbar[t*16+m][c*32+q*8+j]   (sim B operand)
//   zB [(dt*4+kc)*64 + lane][j] = cbar[kc*32+q*8+j][dt*16+m] (z  B operand)
// where m = lane&15, q = lane>>4 (matches mfma_f32_16x16x32_f16 B layout).
__global__ void k_frag(const float* __restrict__ proto,
                       const float* __restrict__ scale,
                       _Float16* __restrict__ simB, _Float16* __restrict__ zB) {
    const int b = blockIdx.x;
    const int lane = threadIdx.x;
    const int m = lane & 15, q = lane >> 4;
    _Float16 r[8];
    if (b < 64) {
        const int t = b >> 3, c = b & 7;
        const int kp = t * 16 + m;
        const float inv = 1.0f / scale[kp];
        const float* src = proto + (size_t)kp * 256 + c * 32 + q * 8;
        #pragma unroll
        for (int j = 0; j < 8; j++) r[j] = (_Float16)(src[j] * inv);
        *(f16x8*)(simB + ((size_t)b * 64 + lane) * 8) = *(const f16x8*)r;
    } else {
        const int b2 = b - 64;
        const int dt = b2 >> 2, kc = b2 & 3;
        #pragma unroll
        for (int j = 0; j < 8; j++) {
            const int kk = kc * 32 + q * 8 + j;
            r[j] = (_Float16)(proto[(size_t)kk * 256 + dt * 16 + m] / scale[kk]);
        }
        *(f16x8*)(zB + ((size_t)b2 * 64 + lane) * 8) = *(const f16x8*)r;
    }
}

// ---------------------------------------------------------------------------
// k_main: 256 threads = 4 independent waves, 16 rows/wave, grid = M/64 = 1024.
// No __syncthreads: pbuf is wave-private (rows w*16..w*16+15), B comes from L2.
__global__ __launch_bounds__(256, 4) void k_main(
    const float* __restrict__ h,
    const float* __restrict__ scale,
    const _Float16* __restrict__ simB,
    const _Float16* __restrict__ zB,
    float* __restrict__ out_p,
    float* __restrict__ out_z) {

    __shared__ _Float16 pbuf[64 * PB_STRIDE];   // 17408 B

    const int tid = threadIdx.x;
    const int w = tid >> 6;
    const int lane = tid & 63;
    const int m = lane & 15;
    const int quad = lane >> 4;
    const int row0 = blockIdx.x * 64 + w * 16;

    // --- load this wave's 16 h-rows (lane quarter-rows), sumsq + raw f16 convert
    const float* hrow = h + (size_t)(row0 + m) * 256 + quad * 8;
    f16x8 A[8];
    float s = 0.f;
    #pragma unroll
    for (int c = 0; c < 8; c++) {
        const float4 a = *(const float4*)(hrow + c * 32);
        const float4 b = *(const float4*)(hrow + c * 32 + 4);
        s += a.x * a.x + a.y * a.y + a.z * a.z + a.w * a.w;
        s += b.x * b.x + b.y * b.y + b.z * b.z + b.w * b.w;
        A[c][0] = (_Float16)a.x; A[c][1] = (_Float16)a.y;
        A[c][2] = (_Float16)a.z; A[c][3] = (_Float16)a.w;
        A[c][4] = (_Float16)b.x; A[c][5] = (_Float16)b.y;
        A[c][6] = (_Float16)b.z; A[c][7] = (_Float16)b.w;
    }
    s += __shfl_xor(s, 16, 64);
    s += __shfl_xor(s, 32, 64);
    const float inv = 1.0f / fmaxf(sqrtf(s), EPS);   // 1/||h[row m]||

    // softmax slope per output row r (rows quad*4+r; their inv lives in lane quad*4+r)
    float tinv[4];
    #pragma unroll
    for (int r = 0; r < 4; r++) tinv[r] = TAU_INV * __shfl(inv, quad * 4 + r, 64);

    // --- sim GEMM on RAW h: acc[t][row r] = h[row]·cbar[t*16+m]
    const f16x8* sB = (const f16x8*)simB;
    f32x4 acc[8] = {};
    #pragma unroll
    for (int t = 0; t < 8; t++) {
        f16x8 Bt[8];
        #pragma unroll
        for (int c = 0; c < 8; c++) Bt[c] = sB[(t * 8 + c) * 64 + lane];
        #pragma unroll
        for (int c = 0; c < 8; c++)
            acc[t] = __builtin_amdgcn_mfma_f32_16x16x32_f16(A[c], Bt[c], acc[t], 0, 0, 0);
    }

    // prototype scales for the z-path A operand (proto = cbar * scale)
    float sc_l[8];
    #pragma unroll
    for (int t = 0; t < 8; t++) sc_l[t] = scale[t * 16 + m];

    // --- softmax over K=128 per row; norm folded into slope tinv[r] (inv>0, max commutes)
    #pragma unroll
    for (int r = 0; r < 4; r++) {
        float mx = acc[0][r];
        #pragma unroll
        for (int t = 1; t < 8; t++) mx = fmaxf(mx, acc[t][r]);
        #pragma unroll
        for (int msk = 1; msk < 16; msk <<= 1) mx = fmaxf(mx, __shfl_xor(mx, msk, 64));
        float e[8];
        float sum = 0.f;
        #pragma unroll
        for (int t = 0; t < 8; t++) {
            e[t] = __expf((acc[t][r] - mx) * tinv[r]);
            sum += e[t];
        }
        #pragma unroll
        for (int msk = 1; msk < 16; msk <<= 1) sum += __shfl_xor(sum, msk, 64);
        const float rs = 1.0f / sum;
        const int grow = row0 + quad * 4 + r;
        float* po = out_p + (size_t)grow * 128;
        const int prow = w * 16 + quad * 4 + r;
        #pragma unroll
        for (int t = 0; t < 8; t++) {
            const float p = e[t] * rs;
            po[t * 16 + m] = p;
            pbuf[prow * PB_STRIDE + t * 16 + m] = (_Float16)(p * sc_l[t]);
        }
    }

    // --- z GEMM: A = (p*scale) fragments from wave-private pbuf (lgkmcnt-ordered,
    // no block barrier), B direct from L2-resident zB fragments.
    f16x8 Ap[4];
    #pragma unroll
    for (int kc = 0; kc < 4; kc++)
        Ap[kc] = *(const f16x8*)&pbuf[(w * 16 + m) * PB_STRIDE + kc * 32 + quad * 8];

    const f16x8* zB8 = (const f16x8*)zB;
    #pragma unroll
    for (int dt = 0; dt < 16; dt++) {
        f16x8 Bz[4];
        #pragma unroll
        for (int kc = 0; kc < 4; kc++) Bz[kc] = zB8[(dt * 4 + kc) * 64 + lane];
        f32x4 zc = {};
        #pragma unroll
        for (int kc = 0; kc < 4; kc++)
            zc = __builtin_amdgcn_mfma_f32_16x16x32_f16(Ap[kc], Bz[kc], zc, 0, 0, 0);
        #pragma unroll
        for (int r = 0; r < 4; r++)
            out_z[(size_t)(row0 + quad * 4 + r) * 256 + dt * 16 + m] = zc[r];
    }
}

// ---------------------------------------------------------------------------
extern "C" void kernel_launch(void* const* d_in, const int* in_sizes, int n_in,
                              void* d_out, int out_size, void* d_ws, size_t ws_size,
                              hipStream_t stream) {
    const float* h_in  = (const float*)d_in[0];   // (B,P,D) fp32, B*P=65536, D=256
    const float* proto = (const float*)d_in[1];   // (K,D) fp32, K=128

    const int M = in_sizes[0] / 256;              // 65536 rows

    // ws: scale[128] f32 (1 KiB slot) | simB (64 KiB) | zB (64 KiB)
    float*     scale = (float*)d_ws;
    _Float16*  simB  = (_Float16*)((char*)d_ws + 1024);
    _Float16*  zB    = (_Float16*)((char*)d_ws + 1024 + 65536);

    float* out_p = (float*)d_out;                 // (M,128)
    float* out_z = out_p + (size_t)M * 128;       // (M,256)

    k_prep<<<dim3(128), dim3(64), 0, stream>>>(proto, scale);
    k_frag<<<dim3(128), dim3(64), 0, stream>>>(proto, scale, simB, zB);
    k_main<<<dim3(M / 64), dim3(256), 0, stream>>>(h_in, scale, simB, zB,
                                                   out_p, out_z);
}